// Round 2
// baseline (1443.796 us; speedup 1.0000x reference)
//
#include <hip/hip_runtime.h>
#include <hip/hip_bf16.h>

#define HID 256
#define NC  19

typedef short short8 __attribute__((ext_vector_type(8)));
typedef float f32x4 __attribute__((ext_vector_type(4)));

__device__ __forceinline__ unsigned short f2bf(float f) {
    unsigned int u = __float_as_uint(f);
    u = (u + 0x7fffu + ((u >> 16) & 1u)) >> 16;
    return (unsigned short)u;
}
__device__ __forceinline__ float bf2f(unsigned short h) {
    return __uint_as_float(((unsigned int)h) << 16);
}

// ---------------- CSR build ----------------

__global__ void hist_kernel(const int* __restrict__ edst, int E, int* __restrict__ deg) {
    int i = blockIdx.x * blockDim.x + threadIdx.x;
    if (i < E) atomicAdd(&deg[edst[i]], 1);
}

__global__ void scanA_kernel(const int* __restrict__ deg, int* __restrict__ offs,
                             int* __restrict__ bsums, int n) {
    __shared__ int s[256];
    int i = blockIdx.x * 256 + threadIdx.x;
    int v = (i < n) ? deg[i] : 0;
    s[threadIdx.x] = v;
    __syncthreads();
    for (int d = 1; d < 256; d <<= 1) {
        int t = (threadIdx.x >= d) ? s[threadIdx.x - d] : 0;
        __syncthreads();
        s[threadIdx.x] += t;
        __syncthreads();
    }
    if (i < n) offs[i] = s[threadIdx.x] - v;
    if (threadIdx.x == 255) bsums[blockIdx.x] = s[255];
}

__global__ void scanB_kernel(int* __restrict__ bsums, int nb) {
    __shared__ int s[256];
    int v = (threadIdx.x < nb) ? bsums[threadIdx.x] : 0;
    s[threadIdx.x] = v;
    __syncthreads();
    for (int d = 1; d < 256; d <<= 1) {
        int t = (threadIdx.x >= d) ? s[threadIdx.x - d] : 0;
        __syncthreads();
        s[threadIdx.x] += t;
        __syncthreads();
    }
    if (threadIdx.x < nb) bsums[threadIdx.x] = s[threadIdx.x] - v;
}

__global__ void scanC_kernel(int* __restrict__ offs, const int* __restrict__ bsums,
                             int* __restrict__ cursor, int n) {
    int i = blockIdx.x * 256 + threadIdx.x;
    if (i < n) {
        int o = offs[i] + bsums[blockIdx.x];
        offs[i] = o;
        cursor[i] = o;
    }
}

__global__ void scatter_kernel(const int* __restrict__ esrc, const int* __restrict__ edst,
                               int E, int* __restrict__ cursor, int* __restrict__ eidx) {
    int i = blockIdx.x * blockDim.x + threadIdx.x;
    if (i < E) {
        int d = edst[i];
        int pos = atomicAdd(&cursor[d], 1);
        eidx[pos] = esrc[i];
    }
}

// ---------------- mean aggregation (wave per dst row) ----------------
// BF16OUT: write bf16 hi/lo planes (for MFMA GEMM). else fp32 mean.
template <bool BF16OUT>
__global__ void aggregate_kernel(const int* __restrict__ eidx, const int* __restrict__ offs,
                                 const int* __restrict__ deg, const float* __restrict__ hsrc,
                                 float* __restrict__ meanf, unsigned short* __restrict__ mh,
                                 unsigned short* __restrict__ ml, int ndst) {
    int d = blockIdx.x * 4 + (threadIdx.x >> 6);
    int lane = threadIdx.x & 63;
    if (d >= ndst) return;
    int start = offs[d];
    int cnt = deg[d];
    float ax = 0.f, ay = 0.f, az = 0.f, aw = 0.f;
    int e = 0;
    for (; e + 2 <= cnt; e += 2) {   // 2-way ILP: two rows in flight
        int s0 = eidx[start + e];
        int s1 = eidx[start + e + 1];
        float4 v0 = *reinterpret_cast<const float4*>(hsrc + (size_t)s0 * HID + lane * 4);
        float4 v1 = *reinterpret_cast<const float4*>(hsrc + (size_t)s1 * HID + lane * 4);
        ax += v0.x + v1.x; ay += v0.y + v1.y; az += v0.z + v1.z; aw += v0.w + v1.w;
    }
    if (e < cnt) {
        int s0 = eidx[start + e];
        float4 v0 = *reinterpret_cast<const float4*>(hsrc + (size_t)s0 * HID + lane * 4);
        ax += v0.x; ay += v0.y; az += v0.z; aw += v0.w;
    }
    float inv = 1.0f / (float)(cnt > 1 ? cnt : 1);
    ax *= inv; ay *= inv; az *= inv; aw *= inv;
    if (BF16OUT) {
        ushort4 h, l;
        h.x = f2bf(ax); l.x = f2bf(ax - bf2f(h.x));
        h.y = f2bf(ay); l.y = f2bf(ay - bf2f(h.y));
        h.z = f2bf(az); l.z = f2bf(az - bf2f(h.z));
        h.w = f2bf(aw); l.w = f2bf(aw - bf2f(h.w));
        *reinterpret_cast<ushort4*>(mh + (size_t)d * HID + lane * 4) = h;
        *reinterpret_cast<ushort4*>(ml + (size_t)d * HID + lane * 4) = l;
    } else {
        float4 o = make_float4(ax, ay, az, aw);
        *reinterpret_cast<float4*>(meanf + (size_t)d * HID + lane * 4) = o;
    }
}

// ---------------- fp32 -> bf16 hi/lo split, row-major [M][256] ----------------
__global__ void conv_rows(const float* __restrict__ src, unsigned short* __restrict__ hi,
                          unsigned short* __restrict__ lo, int n4) {
    int i = blockIdx.x * 256 + threadIdx.x;
    if (i >= n4) return;
    float4 v = reinterpret_cast<const float4*>(src)[i];
    ushort4 h, l;
    h.x = f2bf(v.x); l.x = f2bf(v.x - bf2f(h.x));
    h.y = f2bf(v.y); l.y = f2bf(v.y - bf2f(h.y));
    h.z = f2bf(v.z); l.z = f2bf(v.z - bf2f(h.z));
    h.w = f2bf(v.w); l.w = f2bf(v.w - bf2f(h.w));
    reinterpret_cast<ushort4*>(hi)[i] = h;
    reinterpret_cast<ushort4*>(lo)[i] = l;
}

// ---------------- weight prep: W[512x256] -> transposed bf16 hi/lo [2][256][512] ------
// wt layout per layer: [n][k], k<256 from W_self rows, k>=256 from W_neigh rows.
__global__ void prep_w(const float* __restrict__ Ws0, const float* __restrict__ Wn0,
                       const float* __restrict__ Ws1, const float* __restrict__ Wn1,
                       unsigned short* __restrict__ wth, unsigned short* __restrict__ wtl) {
    int idx = blockIdx.x * 256 + threadIdx.x;      // 0 .. 2*131072-1
    int layer = idx >> 17;
    int t = idx & 131071;
    int n = t >> 9;
    int k = t & 511;
    const float* Ws = layer ? Ws1 : Ws0;
    const float* Wn = layer ? Wn1 : Wn0;
    float v = (k < 256) ? Ws[k * 256 + n] : Wn[(k - 256) * 256 + n];
    unsigned short h = f2bf(v);
    unsigned short l = f2bf(v - bf2f(h));
    wth[idx] = h;
    wtl[idx] = l;
}

// ---------------- MFMA GEMM (zero-LDS, 4-term bf16 split) ----------------
// C[M x 256] = relu?([hdst|mean][M x 512] @ Wt^T + b)
// Split: A=Ah+Al, W=Wh+Wl; sum of 4 products == logical K=2048, 64 steps of 32.
// step s: phase p=s>>4; A plane hi for p<2, lo for p>=2; W plane hi for p even, lo for p odd.
// Block: 256 thr = 4 waves (2x2), BM=BN=128, wave tile 64x64 = 4x4 frags of 16x16.
#define MFMA16(A, B)                                                                   \
    _Pragma("unroll") for (int mi = 0; mi < 4; ++mi)                                   \
        _Pragma("unroll") for (int ni = 0; ni < 4; ++ni)                               \
            acc[mi][ni] = __builtin_amdgcn_mfma_f32_16x16x32_bf16(A[mi], B[ni],        \
                                                                  acc[mi][ni], 0, 0, 0);

template <bool RELU>
__global__ __launch_bounds__(256, 2) void mfma_gemm(
    const unsigned short* __restrict__ Ahd, const unsigned short* __restrict__ Ald,
    const unsigned short* __restrict__ Ahm, const unsigned short* __restrict__ Alm,
    const unsigned short* __restrict__ Wh, const unsigned short* __restrict__ Wl,
    const float* __restrict__ bias, float* __restrict__ out, int M) {
    const int lane = threadIdx.x & 63;
    const int w = threadIdx.x >> 6;
    const int wr = w >> 1, wc = w & 1;
    const int r0 = blockIdx.x * 128 + wr * 64;
    const int c0 = blockIdx.y * 128 + wc * 64;
    const int lrow = lane & 15;
    const int lkg8 = (lane >> 4) * 8;

    size_t aoff[4], boff[4];
#pragma unroll
    for (int mi = 0; mi < 4; ++mi) aoff[mi] = (size_t)(r0 + mi * 16 + lrow) * HID + lkg8;
#pragma unroll
    for (int ni = 0; ni < 4; ++ni) boff[ni] = (size_t)(c0 + ni * 16 + lrow) * 512 + lkg8;

    f32x4 acc[4][4];
#pragma unroll
    for (int mi = 0; mi < 4; ++mi)
#pragma unroll
        for (int ni = 0; ni < 4; ++ni) acc[mi][ni] = (f32x4)(0.f);

    auto getA = [&](int s, int mi) -> short8 {
        int k512 = (s & 15) * 32;
        const unsigned short* plane =
            (s < 32) ? (k512 < 256 ? Ahd : Ahm) : (k512 < 256 ? Ald : Alm);
        return *reinterpret_cast<const short8*>(plane + aoff[mi] + (k512 & 255));
    };
    auto getB = [&](int s, int ni) -> short8 {
        const unsigned short* plane = (s & 16) ? Wl : Wh;
        return *reinterpret_cast<const short8*>(plane + boff[ni] + (s & 15) * 32);
    };

    short8 a0[4], b0[4], a1[4], b1[4];
#pragma unroll
    for (int i = 0; i < 4; ++i) { a0[i] = getA(0, i); b0[i] = getB(0, i); }

    for (int s = 0; s < 64; s += 2) {
#pragma unroll
        for (int i = 0; i < 4; ++i) { a1[i] = getA(s + 1, i); b1[i] = getB(s + 1, i); }
        MFMA16(a0, b0);
        if (s + 2 < 64) {
#pragma unroll
            for (int i = 0; i < 4; ++i) { a0[i] = getA(s + 2, i); b0[i] = getB(s + 2, i); }
        }
        MFMA16(a1, b1);
    }

#pragma unroll
    for (int ni = 0; ni < 4; ++ni) {
        int col = c0 + ni * 16 + lrow;
        float bv = bias[col];
#pragma unroll
        for (int mi = 0; mi < 4; ++mi) {
            int row0 = r0 + mi * 16 + (lane >> 4) * 4;
#pragma unroll
            for (int j = 0; j < 4; ++j) {
                float v = acc[mi][ni][j] + bv;
                if (RELU) v = fmaxf(v, 0.f);
                out[(size_t)(row0 + j) * HID + col] = v;
            }
        }
    }
}

// ---------------- final layer: M=512, K=2x256, N=19, fp32, no relu ----------------
__global__ void out_gemm(const float* __restrict__ hdst, const float* __restrict__ mean,
                         const float* __restrict__ Wself, const float* __restrict__ Wneigh,
                         const float* __restrict__ bias, float* __restrict__ out) {
    int r = blockIdx.x;
    int lane = threadIdx.x;
    if (lane >= NC) return;
    const float* hr = hdst + (size_t)r * HID;
    const float* mr = mean + (size_t)r * HID;
    float s0 = 0.f, s1 = 0.f, s2 = 0.f, s3 = 0.f;
    for (int k = 0; k < HID; k += 4) {
        s0 = fmaf(hr[k],     Wself[(k)     * NC + lane], s0);
        s1 = fmaf(hr[k + 1], Wself[(k + 1) * NC + lane], s1);
        s2 = fmaf(hr[k + 2], Wself[(k + 2) * NC + lane], s2);
        s3 = fmaf(hr[k + 3], Wself[(k + 3) * NC + lane], s3);
    }
    for (int k = 0; k < HID; k += 4) {
        s0 = fmaf(mr[k],     Wneigh[(k)     * NC + lane], s0);
        s1 = fmaf(mr[k + 1], Wneigh[(k + 1) * NC + lane], s1);
        s2 = fmaf(mr[k + 2], Wneigh[(k + 2) * NC + lane], s2);
        s3 = fmaf(mr[k + 3], Wneigh[(k + 3) * NC + lane], s3);
    }
    out[r * NC + lane] = s0 + s1 + s2 + s3 + bias[lane];
}

// ---------------- launcher ----------------

extern "C" void kernel_launch(void* const* d_in, const int* in_sizes, int n_in,
                              void* d_out, int out_size, void* d_ws, size_t ws_size,
                              hipStream_t stream) {
    const float* x   = (const float*)d_in[0];
    const int* esrc0 = (const int*)d_in[1];
    const int* edst0 = (const int*)d_in[2];
    const int* esrc1 = (const int*)d_in[3];
    const int* edst1 = (const int*)d_in[4];
    const int* esrc2 = (const int*)d_in[5];
    const int* edst2 = (const int*)d_in[6];
    const float* Ws0 = (const float*)d_in[7];
    const float* Wn0 = (const float*)d_in[8];
    const float* b0  = (const float*)d_in[9];
    const float* Ws1 = (const float*)d_in[10];
    const float* Wn1 = (const float*)d_in[11];
    const float* b1  = (const float*)d_in[12];
    const float* Ws2 = (const float*)d_in[13];
    const float* Wn2 = (const float*)d_in[14];
    const float* b2  = (const float*)d_in[15];

    const int NDST0 = 61952, NDST1 = 5632, NDST2 = 512;
    const int E0 = in_sizes[1], E1 = in_sizes[3], E2 = in_sizes[5];

    char* ws = (char*)d_ws;
    size_t off = 0;
    auto alloc = [&](size_t bytes) -> void* {
        void* p = ws + off;
        off += (bytes + 255) & ~(size_t)255;
        return p;
    };
    // bf16 planes
    unsigned short* xh  = (unsigned short*)alloc((size_t)NDST0 * HID * 2);
    unsigned short* xl  = (unsigned short*)alloc((size_t)NDST0 * HID * 2);
    unsigned short* mh0 = (unsigned short*)alloc((size_t)NDST0 * HID * 2);
    unsigned short* ml0 = (unsigned short*)alloc((size_t)NDST0 * HID * 2);
    unsigned short* h1h = (unsigned short*)alloc((size_t)NDST1 * HID * 2);
    unsigned short* h1l = (unsigned short*)alloc((size_t)NDST1 * HID * 2);
    unsigned short* mh1 = (unsigned short*)alloc((size_t)NDST1 * HID * 2);
    unsigned short* ml1 = (unsigned short*)alloc((size_t)NDST1 * HID * 2);
    unsigned short* wth = (unsigned short*)alloc((size_t)2 * 256 * 512 * 2);
    unsigned short* wtl = (unsigned short*)alloc((size_t)2 * 256 * 512 * 2);
    // fp32 intermediates
    float* h1    = (float*)alloc((size_t)NDST0 * HID * 4);
    float* h2    = (float*)alloc((size_t)NDST1 * HID * 4);
    float* mean2 = (float*)alloc((size_t)NDST2 * HID * 4);
    // CSR scratch
    int* eidx   = (int*)alloc((size_t)E0 * 4);
    int* deg    = (int*)alloc((size_t)NDST0 * 4);
    int* offs   = (int*)alloc((size_t)NDST0 * 4);
    int* cursor = (int*)alloc((size_t)NDST0 * 4);
    int* bsums  = (int*)alloc(1024);

    auto run_csr = [&](const int* esrc, const int* edst, int E, int ndst) {
        hipMemsetAsync(deg, 0, (size_t)ndst * 4, stream);
        hist_kernel<<<dim3((E + 255) / 256), dim3(256), 0, stream>>>(edst, E, deg);
        int nb = (ndst + 255) / 256;
        scanA_kernel<<<dim3(nb), dim3(256), 0, stream>>>(deg, offs, bsums, ndst);
        scanB_kernel<<<dim3(1), dim3(256), 0, stream>>>(bsums, nb);
        scanC_kernel<<<dim3(nb), dim3(256), 0, stream>>>(offs, bsums, cursor, ndst);
        scatter_kernel<<<dim3((E + 255) / 256), dim3(256), 0, stream>>>(esrc, edst, E, cursor, eidx);
    };

    // weight prep + x split (independent of CSR)
    prep_w<<<dim3(1024), dim3(256), 0, stream>>>(Ws0, Wn0, Ws1, Wn1, wth, wtl);
    conv_rows<<<dim3(NDST0 * HID / 4 / 256), dim3(256), 0, stream>>>(x, xh, xl, NDST0 * HID / 4);

    // Layer 0
    run_csr(esrc0, edst0, E0, NDST0);
    aggregate_kernel<true><<<dim3((NDST0 + 3) / 4), dim3(256), 0, stream>>>(
        eidx, offs, deg, x, nullptr, mh0, ml0, NDST0);
    mfma_gemm<true><<<dim3(NDST0 / 128, 2), dim3(256), 0, stream>>>(
        xh, xl, mh0, ml0, wth, wtl, b0, h1, NDST0);

    // Layer 1
    conv_rows<<<dim3(NDST1 * HID / 4 / 256), dim3(256), 0, stream>>>(h1, h1h, h1l, NDST1 * HID / 4);
    run_csr(esrc1, edst1, E1, NDST1);
    aggregate_kernel<true><<<dim3((NDST1 + 3) / 4), dim3(256), 0, stream>>>(
        eidx, offs, deg, h1, nullptr, mh1, ml1, NDST1);
    mfma_gemm<true><<<dim3(NDST1 / 128, 2), dim3(256), 0, stream>>>(
        h1h, h1l, mh1, ml1, wth + 131072, wtl + 131072, b1, h2, NDST1);

    // Layer 2 (fp32 throughout)
    run_csr(esrc2, edst2, E2, NDST2);
    aggregate_kernel<false><<<dim3((NDST2 + 3) / 4), dim3(256), 0, stream>>>(
        eidx, offs, deg, h2, mean2, nullptr, nullptr, NDST2);
    out_gemm<<<dim3(512), dim3(64), 0, stream>>>(h2, mean2, Ws2, Wn2, b2, (float*)d_out);
}